// Round 4
// baseline (54.808 us; speedup 1.0000x reference)
//
#include <hip/hip_runtime.h>

#define N  35
#define E  (N*N)
#define C1 256
#define C2 256
#define C3 128

// Workspace layout (floats):
//   h1   @ 0     : 35*256 = 8960
//   agg2 @ 8960  : 35*256 = 8960   (accumulators, zeroed by k_layer1 each call;
//   agg3 @ 17920 : 35*128 = 4480    hold PRE-activation: msg/35 + h@root. bias+relu at read.)

// ---------------- Layer 1: cin=1, cout=256 (also zeroes agg2/agg3) ----------------
__global__ __launch_bounds__(C1) void k_layer1(
    const float* __restrict__ x, const float* __restrict__ ea,
    const float* __restrict__ nn1w, const float* __restrict__ nn1b,
    const float* __restrict__ root1, const float* __restrict__ bias1,
    float* __restrict__ h1, float* __restrict__ aggz)
{
    // zero the agg2+agg3 accumulators (13440 floats); stream order makes this
    // visible to k_l2/k_l3 which run strictly after this kernel.
    for (int t = blockIdx.x * blockDim.x + threadIdx.x; t < 8960 + 4480;
         t += gridDim.x * blockDim.x)
        aggz[t] = 0.f;

    int j = blockIdx.x;
    int o = threadIdx.x;
    float w[6];
#pragma unroll
    for (int v = 0; v < 6; ++v) w[v] = nn1w[v * C1 + o];
    float b = nn1b[o];
    float acc = 0.f;
    for (int i = 0; i < N; ++i) {
        const float* ep = ea + (i * N + j) * 6;   // j uniform -> s_load
        float p = b;
#pragma unroll
        for (int v = 0; v < 6; ++v) p = fmaf(ep[v], w[v], p);
        p = fmaxf(p, 0.f);
        acc = fmaf(x[i], p, acc);
    }
    float s = acc * (1.f / N) + x[j] * root1[o] + bias1[o];
    h1[j * C1 + o] = fmaxf(s, 0.f);
}

// ---------------- Layer 2: msg chunks (32 x 8c) + root chunks (8 x 32c) ----------------
// All ea/h1 inner-loop operands are block-uniform -> scalar loads, no LDS, no barrier.
__global__ __launch_bounds__(256) void k_l2(
    const float* __restrict__ ea,
    const float* __restrict__ w2, const float* __restrict__ b2,
    const float* __restrict__ h1, const float* __restrict__ root2,
    float* __restrict__ agg2)
{
    const int j     = blockIdx.x % N;
    const int chunk = blockIdx.x / N;   // 0..39
    const int o     = threadIdx.x;

    if (chunk < 32) {
        const int c0 = chunk * 8;

        float wv[8][6], bb[8], acc[8];
#pragma unroll
        for (int cc = 0; cc < 8; ++cc) {
            int col = (c0 + cc) * C2 + o;
#pragma unroll
            for (int v = 0; v < 6; ++v) wv[cc][v] = w2[v * (C1 * C2) + col];
            bb[cc] = b2[col];
            acc[cc] = 0.f;
        }

        const int eb = j * 6;
#pragma unroll 5
        for (int i = 0; i < N; ++i) {
            const float* ep = ea + i * (N * 6) + eb;   // uniform
            const float e0 = ep[0], e1 = ep[1], e2 = ep[2];
            const float e3 = ep[3], e4 = ep[4], e5 = ep[5];
            const float* hp = h1 + i * C1 + c0;        // uniform
            float hv[8];
#pragma unroll
            for (int cc = 0; cc < 8; ++cc) hv[cc] = hp[cc];
#pragma unroll
            for (int cc = 0; cc < 8; ++cc) {
                float p = fmaf(e0, wv[cc][0], bb[cc]);
                p = fmaf(e1, wv[cc][1], p);
                p = fmaf(e2, wv[cc][2], p);
                p = fmaf(e3, wv[cc][3], p);
                p = fmaf(e4, wv[cc][4], p);
                p = fmaf(e5, wv[cc][5], p);
                p = fmaxf(p, 0.f);
                acc[cc] = fmaf(hv[cc], p, acc[cc]);
            }
        }
        float s = 0.f;
#pragma unroll
        for (int cc = 0; cc < 8; ++cc) s += acc[cc];
        atomicAdd(&agg2[j * C2 + o], s * (1.f / N));
    } else {
        // root contribution: 32 c's per chunk
        const int c0 = (chunk - 32) * 32;
        float s = 0.f;
#pragma unroll 8
        for (int c = c0; c < c0 + 32; ++c)
            s = fmaf(h1[j * C1 + c], root2[c * C2 + o], s);   // h1[j*C1+c] uniform
        atomicAdd(&agg2[j * C2 + o], s);
    }
}

// ---------------- Layer 3: msg chunks (32 x 8c) + root chunks (4 x 64c) ----------------
// h2(i,c) = relu(agg2[i,c] + bias2[c]) computed on the fly (uniform scalar loads).
__global__ __launch_bounds__(256) void k_l3(
    const float* __restrict__ ea,
    const float* __restrict__ w3, const float* __restrict__ b3,
    const float* __restrict__ agg2, const float* __restrict__ bias2,
    const float* __restrict__ root3,
    float* __restrict__ agg3)
{
    const int j     = blockIdx.x % N;
    const int chunk = blockIdx.x / N;   // 0..35
    const int tid   = threadIdx.x;
    const int o     = tid & (C3 - 1);
    const int half  = tid >> 7;         // wave-uniform (waves 0-1 vs 2-3)

    if (chunk < 32) {
        const int c0 = chunk * 8;

        float wv[8][6], bb[8], acc[8];
#pragma unroll
        for (int cc = 0; cc < 8; ++cc) {
            int col = (c0 + cc) * C3 + o;
#pragma unroll
            for (int v = 0; v < 6; ++v) wv[cc][v] = w3[v * (C2 * C3) + col];
            bb[cc] = b3[col];
            acc[cc] = 0.f;
        }

        const int eb = j * 6;
        const int ibeg = half ? 18 : 0;
        const int iend = half ? N  : 18;
        for (int i = ibeg; i < iend; ++i) {
            const float* ep = ea + i * (N * 6) + eb;   // uniform
            const float e0 = ep[0], e1 = ep[1], e2 = ep[2];
            const float e3 = ep[3], e4 = ep[4], e5 = ep[5];
            const float* ap = agg2 + i * C2 + c0;      // uniform
            const float* bp = bias2 + c0;              // uniform
            float hv[8];
#pragma unroll
            for (int cc = 0; cc < 8; ++cc) hv[cc] = fmaxf(ap[cc] + bp[cc], 0.f);
#pragma unroll
            for (int cc = 0; cc < 8; ++cc) {
                float p = fmaf(e0, wv[cc][0], bb[cc]);
                p = fmaf(e1, wv[cc][1], p);
                p = fmaf(e2, wv[cc][2], p);
                p = fmaf(e3, wv[cc][3], p);
                p = fmaf(e4, wv[cc][4], p);
                p = fmaf(e5, wv[cc][5], p);
                p = fmaxf(p, 0.f);
                acc[cc] = fmaf(hv[cc], p, acc[cc]);
            }
        }
        float s = 0.f;
#pragma unroll
        for (int cc = 0; cc < 8; ++cc) s += acc[cc];
        atomicAdd(&agg3[j * C3 + o], s * (1.f / N));
    } else {
        // root contribution: 64 c's per chunk, 32 per half
        const int c0 = (chunk - 32) * 64 + half * 32;
        float s = 0.f;
#pragma unroll 8
        for (int c = c0; c < c0 + 32; ++c) {
            float hvv = fmaxf(agg2[j * C2 + c] + bias2[c], 0.f);  // uniform
            s = fmaf(hvv, root3[c * C3 + o], s);
        }
        atomicAdd(&agg3[j * C3 + o], s);
    }
}

// ---------------- CBT: pairwise L1 distance, h3 = relu(agg3+bias3) on the fly ----------------
__global__ __launch_bounds__(256) void k_cbt(
    const float* __restrict__ agg3, const float* __restrict__ bias3,
    float* __restrict__ out)
{
    int t = blockIdx.x * 256 + threadIdx.x;
    if (t >= E) return;
    int i = t / N, j = t % N;
    float acc = 0.f;
#pragma unroll
    for (int f = 0; f < C3 / 4; ++f) {
        float4 a  = *(const float4*)&agg3[i * C3 + f * 4];
        float4 b  = *(const float4*)&agg3[j * C3 + f * 4];
        float4 bi = *(const float4*)&bias3[f * 4];
        float ax = fmaxf(a.x + bi.x, 0.f), bx = fmaxf(b.x + bi.x, 0.f);
        float ay = fmaxf(a.y + bi.y, 0.f), by = fmaxf(b.y + bi.y, 0.f);
        float az = fmaxf(a.z + bi.z, 0.f), bz = fmaxf(b.z + bi.z, 0.f);
        float aw = fmaxf(a.w + bi.w, 0.f), bw = fmaxf(b.w + bi.w, 0.f);
        acc += fabsf(bx - ax) + fabsf(by - ay) + fabsf(bz - az) + fabsf(bw - aw);
    }
    out[t] = acc;
}

extern "C" void kernel_launch(void* const* d_in, const int* in_sizes, int n_in,
                              void* d_out, int out_size, void* d_ws, size_t ws_size,
                              hipStream_t stream)
{
    const float* x     = (const float*)d_in[0];
    const float* ea    = (const float*)d_in[1];
    // d_in[2] = edge_index, unused: topology is static (src=e/35, dst=e%35)
    const float* nn1w  = (const float*)d_in[3];
    const float* nn1b  = (const float*)d_in[4];
    const float* nn2w  = (const float*)d_in[5];
    const float* nn2b  = (const float*)d_in[6];
    const float* nn3w  = (const float*)d_in[7];
    const float* nn3b  = (const float*)d_in[8];
    const float* root1 = (const float*)d_in[9];
    const float* bias1 = (const float*)d_in[10];
    const float* root2 = (const float*)d_in[11];
    const float* bias2 = (const float*)d_in[12];
    const float* root3 = (const float*)d_in[13];
    const float* bias3 = (const float*)d_in[14];

    float* ws   = (float*)d_ws;
    float* h1   = ws;
    float* agg2 = ws + 8960;
    float* agg3 = ws + 8960 + 8960;

    // k_layer1 zeroes agg2+agg3 (contiguous) at entry — no memset node needed.
    k_layer1<<<N, C1, 0, stream>>>(x, ea, nn1w, nn1b, root1, bias1, h1, agg2);
    k_l2<<<N * 40, 256, 0, stream>>>(ea, nn2w, nn2b, h1, root2, agg2);
    k_l3<<<N * 36, 256, 0, stream>>>(ea, nn3w, nn3b, agg2, bias2, root3, agg3);
    k_cbt<<<(E + 255) / 256, 256, 0, stream>>>(agg3, bias3, (float*)d_out);
}